// Round 6
// baseline (32.822 us; speedup 1.0000x reference)
//
#include <hip/hip_runtime.h>

#define DEV __device__ __forceinline__

typedef unsigned u32;
typedef u32 u32x2 __attribute__((ext_vector_type(2)));

// ---------- DPP helpers (ctrl/masks as template params: builtin needs ICEs) ----------
// update_dpp(old, src, ctrl, row_mask, bank_mask, bound): enabled lanes get
// src[dpp-mapped lane]; mask-disabled lanes KEEP old. 64 lanes = 4 rows x 16;
// bank = 4 lanes within row.

template<int CTRL>
DEV int dpp_full(int src) {
    return __builtin_amdgcn_update_dpp(src, src, CTRL, 0xF, 0xF, false);
}

template<int CTRL, int RM, int BM>
DEV int dpp_masked(int old, int src) {
    return __builtin_amdgcn_update_dpp(old, src, CTRL, RM, BM, false);
}

// ---------- cross-lane xor-shuffle, zero DS ----------
// xor1 = quad_perm[1,0,3,2] (0xB1); xor2 = quad_perm[2,3,0,1] (0x4E);
// xor4 = xor3 (quad_perm[3,2,1,0]=0x1B) then xor7 (row_half_mirror=0x141);
// xor8 = row_ror:8 (0x128); xor16 = permlane16_swap; xor32 = permlane32_swap.

template<int B>
DEV float lshfl(float x, bool p32, bool p16) {
    int xi = __float_as_int(x);
    if constexpr (B == 0) {
        return __int_as_float(dpp_full<0xB1>(xi));
    } else if constexpr (B == 1) {
        return __int_as_float(dpp_full<0x4E>(xi));
    } else if constexpr (B == 2) {
        return __int_as_float(dpp_full<0x141>(dpp_full<0x1B>(xi)));
    } else if constexpr (B == 3) {
        return __int_as_float(dpp_full<0x128>(xi));
    } else if constexpr (B == 4) {
#if __has_builtin(__builtin_amdgcn_permlane16_swap)
        u32x2 r = __builtin_amdgcn_permlane16_swap((u32)xi, (u32)xi, false, false);
        return __int_as_float((int)(p16 ? r.x : r.y));
#else
        return __int_as_float(__builtin_amdgcn_ds_swizzle(xi, 0x401F));
#endif
    } else {
        u32x2 r = __builtin_amdgcn_permlane32_swap((u32)xi, (u32)xi, false, false);
        return __int_as_float((int)(p32 ? r.x : r.y));
    }
}

// Convention-independent probes: which pair element holds the OTHER group's value.
DEV bool probe32(int lane) {
    u32 p = (u32)((lane >> 5) & 1);
    u32x2 r = __builtin_amdgcn_permlane32_swap(p, p, false, false);
    return r.x == (p ^ 1u);
}
DEV bool probe16(int lane) {
#if __has_builtin(__builtin_amdgcn_permlane16_swap)
    u32 p = (u32)((lane >> 4) & 1);
    u32x2 r = __builtin_amdgcn_permlane16_swap(p, p, false, false);
    return r.x == (p ^ 1u);
#else
    return false;
#endif
}

// ---------- complex pair primitives (fp32 scalars) ----------

DEV void rx_pair(float& r0, float& i0, float& r1, float& i1, float c, float s) {
    float nr0 = fmaf(c, r0,  s * i1);
    float ni0 = fmaf(c, i0, -s * r1);
    float nr1 = fmaf(c, r1,  s * i0);
    float ni1 = fmaf(c, i1, -s * r0);
    r0 = nr0; i0 = ni0; r1 = nr1; i1 = ni1;
}

DEV void ry_pair(float& r0, float& i0, float& r1, float& i1, float c, float s) {
    float nr0 = fmaf(c, r0, -s * r1);
    float ni0 = fmaf(c, i0, -s * i1);
    float nr1 = fmaf(c, r1,  s * r0);
    float ni1 = fmaf(c, i1,  s * i0);
    r0 = nr0; i0 = ni0; r1 = nr1; i1 = ni1;
}

DEV void rz_amp(float& r, float& i, float c, float ss) {
    float nr = fmaf(c, r, -ss * i);
    float ni = fmaf(c, i,  ss * r);
    r = nr; i = ni;
}

// ---------- gates on flat-index bit B (B = 7 - qubit) ----------
// layout: amp idx = k*64 + lane; bits 0..5 = lane bits, 6 = k bit0, 7 = k bit1

template<int B>
DEV void apply_rx(float (&re)[4], float (&im)[4], int lane, bool p32, bool p16,
                  float c, float s) {
    if constexpr (B == 7) {
        rx_pair(re[0], im[0], re[2], im[2], c, s);
        rx_pair(re[1], im[1], re[3], im[3], c, s);
    } else if constexpr (B == 6) {
        rx_pair(re[0], im[0], re[1], im[1], c, s);
        rx_pair(re[2], im[2], re[3], im[3], c, s);
    } else {
#pragma unroll
        for (int k = 0; k < 4; ++k) {
            float pr = lshfl<B>(re[k], p32, p16);
            float pi = lshfl<B>(im[k], p32, p16);
            re[k] = fmaf(c, re[k],  s * pi);   // RX symmetric: no hi/lo branch
            im[k] = fmaf(c, im[k], -s * pr);
        }
    }
}

template<int B>
DEV void apply_ry(float (&re)[4], float (&im)[4], int lane, bool p32, bool p16,
                  float c, float s) {
    if constexpr (B == 7) {
        ry_pair(re[0], im[0], re[2], im[2], c, s);
        ry_pair(re[1], im[1], re[3], im[3], c, s);
    } else if constexpr (B == 6) {
        ry_pair(re[0], im[0], re[1], im[1], c, s);
        ry_pair(re[2], im[2], re[3], im[3], c, s);
    } else {
        float ssel = ((lane >> B) & 1) ? s : -s;
#pragma unroll
        for (int k = 0; k < 4; ++k) {
            float pr = lshfl<B>(re[k], p32, p16);
            float pi = lshfl<B>(im[k], p32, p16);
            re[k] = fmaf(c, re[k], ssel * pr);
            im[k] = fmaf(c, im[k], ssel * pi);
        }
    }
}

template<int B>
DEV void apply_rz(float (&re)[4], float (&im)[4], int lane, float c, float s) {
    if constexpr (B == 7) {
        rz_amp(re[0], im[0], c, -s); rz_amp(re[1], im[1], c, -s);
        rz_amp(re[2], im[2], c,  s); rz_amp(re[3], im[3], c,  s);
    } else if constexpr (B == 6) {
        rz_amp(re[0], im[0], c, -s); rz_amp(re[1], im[1], c,  s);
        rz_amp(re[2], im[2], c, -s); rz_amp(re[3], im[3], c,  s);
    } else {
        float ss = ((lane >> B) & 1) ? s : -s;
#pragma unroll
        for (int k = 0; k < 4; ++k) rz_amp(re[k], im[k], c, ss);
    }
}

// CNOT(ctrl=BC, tgt=BT): lanes with ctrl-bit=1 take partner's value (xor BT),
// others unchanged. Masked DPP does the conditional update in ONE instruction.
template<int BC, int BT>
DEV void apply_cnot(float (&re)[4], float (&im)[4], int lane, bool p32, bool p16) {
    if constexpr (BC == 7 && BT == 6) {
        // ctrl = k bit1, tgt = k bit0: swap k=2 <-> k=3 (register rename)
        float tr = re[2], ti = im[2];
        re[2] = re[3]; im[2] = im[3];
        re[3] = tr;    im[3] = ti;
    } else if constexpr (BC == 6) {
        // ctrl = k bit0 (k=1,3 always on): unconditional xor32 swap
        re[1] = lshfl<BT>(re[1], p32, p16); im[1] = lshfl<BT>(im[1], p32, p16);
        re[3] = lshfl<BT>(re[3], p32, p16); im[3] = lshfl<BT>(im[3], p32, p16);
    } else if constexpr (BC == 5 && BT == 4) {
        // ctrl = lane bit5: permlane16_swap partner + cndmask
        bool ctrl = (lane >> 5) & 1;
#pragma unroll
        for (int k = 0; k < 4; ++k) {
            float pr = lshfl<4>(re[k], p32, p16);
            float pi = lshfl<4>(im[k], p32, p16);
            re[k] = ctrl ? pr : re[k];
            im[k] = ctrl ? pi : im[k];
        }
    } else if constexpr (BC == 4 && BT == 3) {
        // ctrl = lane bit4 = rows 1,3 -> row_mask 0xA; xor8 = row_ror:8
#pragma unroll
        for (int k = 0; k < 4; ++k) {
            int r = __float_as_int(re[k]), i = __float_as_int(im[k]);
            re[k] = __int_as_float(dpp_masked<0x128, 0xA, 0xF>(r, r));
            im[k] = __int_as_float(dpp_masked<0x128, 0xA, 0xF>(i, i));
        }
    } else if constexpr (BC == 3 && BT == 2) {
        // ctrl = lane bit3 = banks 2,3 -> bank_mask 0xC on 2nd DPP of xor4 pair
#pragma unroll
        for (int k = 0; k < 4; ++k) {
            int r = __float_as_int(re[k]), i = __float_as_int(im[k]);
            int tr = dpp_full<0x1B>(r), ti = dpp_full<0x1B>(i);   // xor3, all lanes
            re[k] = __int_as_float(dpp_masked<0x141, 0xF, 0xC>(r, tr));
            im[k] = __int_as_float(dpp_masked<0x141, 0xF, 0xC>(i, ti));
        }
    } else if constexpr (BC == 2 && BT == 1) {
        // ctrl = lane bit2 = banks 1,3 -> bank_mask 0xA; xor2 = quad_perm 0x4E
#pragma unroll
        for (int k = 0; k < 4; ++k) {
            int r = __float_as_int(re[k]), i = __float_as_int(im[k]);
            re[k] = __int_as_float(dpp_masked<0x4E, 0xF, 0xA>(r, r));
            im[k] = __int_as_float(dpp_masked<0x4E, 0xF, 0xA>(i, i));
        }
    } else {
        // BC==1, BT==0: quad_perm [0,1,3,2] = 0xB4 encodes the conditional swap
#pragma unroll
        for (int k = 0; k < 4; ++k) {
            re[k] = __int_as_float(dpp_full<0xB4>(__float_as_int(re[k])));
            im[k] = __int_as_float(dpp_full<0xB4>(__float_as_int(im[k])));
        }
    }
}

// ---------- uniform coefficient broadcast: VGPR lane -> SGPR ----------

DEV float rl(float v, int idx) {
    return __int_as_float(__builtin_amdgcn_readlane(__float_as_int(v), idx));
}

// ---------- main: one wave per batch element, single kernel ----------

__global__ __launch_bounds__(256, 8) void qa_sim(
    const float* __restrict__ x, const float* __restrict__ params,
    float* __restrict__ out, int batch)
{
    int tid  = blockIdx.x * 256 + threadIdx.x;
    int b    = tid >> 6;
    int lane = threadIdx.x & 63;
    if (b >= batch) return;

    bool p32 = probe32(lane);
    bool p16 = probe16(lane);

    // per-lane angle table: lanes 0..47 -> shared params, 48..55 -> this x row
    float pv = 0.f;
    if (lane < 48)      pv = params[lane];
    else if (lane < 56) pv = x[b * 8 + (lane - 48)];
    float th = pv * 0.5f;
    float cv = __cosf(th);
    float sv = __sinf(th);

    float re[4], im[4];
    re[0] = (lane == 0) ? 1.f : 0.f;
    re[1] = re[2] = re[3] = 0.f;
    im[0] = im[1] = im[2] = im[3] = 0.f;

    // ---- data encoding: RX(x[b,i]) on qubit i (bit 7-i) ----
#define ENC(i) apply_rx<7 - (i)>(re, im, lane, p32, p16, rl(cv, 48 + (i)), rl(sv, 48 + (i)));
    ENC(0) ENC(1) ENC(2) ENC(3) ENC(4) ENC(5) ENC(6) ENC(7)
#undef ENC

    // ---- variational layers: params[l][i][{RY,RZ,RX}] ----
#define VQ(l, i) { const int j = (l) * 24 + (i) * 3;                             \
                   apply_ry<7 - (i)>(re, im, lane, p32, p16, rl(cv, j), rl(sv, j)); \
                   apply_rz<7 - (i)>(re, im, lane, rl(cv, j + 1), rl(sv, j + 1)); }
#define CN(i)    apply_cnot<7 - (i), 6 - (i)>(re, im, lane, p32, p16);
#define RXQ(l,i) { const int j = (l) * 24 + (i) * 3 + 2;                         \
                   apply_rx<7 - (i)>(re, im, lane, p32, p16, rl(cv, j), rl(sv, j)); }
#define LAYER(l) \
    VQ(l,0) CN(0) VQ(l,1) CN(1) VQ(l,2) CN(2) VQ(l,3) CN(3) \
    VQ(l,4) CN(4) VQ(l,5) CN(5) VQ(l,6) CN(6) VQ(l,7)       \
    RXQ(l,0) RXQ(l,1) RXQ(l,2) RXQ(l,3) RXQ(l,4) RXQ(l,5) RXQ(l,6) RXQ(l,7)

    LAYER(0)
    LAYER(1)
#undef LAYER
#undef RXQ
#undef CN
#undef VQ

    // ---- <Z_i> readout ----
    float p0 = fmaf(re[0], re[0], im[0] * im[0]);
    float p1 = fmaf(re[1], re[1], im[1] * im[1]);
    float p2 = fmaf(re[2], re[2], im[2] * im[2]);
    float p3 = fmaf(re[3], re[3], im[3] * im[3]);

    float z0 = (p0 + p1) - (p2 + p3);   // qubit0 = bit7 = k bit1
    float z1 = (p0 - p1) + (p2 - p3);   // qubit1 = bit6 = k bit0
    float A  = (p0 + p1) + (p2 + p3);   // total prob per lane

    z0 += lshfl<0>(z0, p32, p16); z1 += lshfl<0>(z1, p32, p16);
    z0 += lshfl<1>(z0, p32, p16); z1 += lshfl<1>(z1, p32, p16);
    z0 += lshfl<2>(z0, p32, p16); z1 += lshfl<2>(z1, p32, p16);
    z0 += lshfl<3>(z0, p32, p16); z1 += lshfl<3>(z1, p32, p16);
    z0 += lshfl<4>(z0, p32, p16); z1 += lshfl<4>(z1, p32, p16);
    z0 += lshfl<5>(z0, p32, p16); z1 += lshfl<5>(z1, p32, p16);

    // pruned Walsh-Hadamard on A: D_b = signed sum over lane bit b
    float S = A, P, D0, D1, D2, D3, D4, D5;
    P = lshfl<0>(S, p32, p16); D0 = S - P; S += P;
    P = lshfl<1>(S, p32, p16); D1 = S - P; S += P;
    P = lshfl<2>(S, p32, p16); D2 = S - P; S += P;
    P = lshfl<3>(S, p32, p16); D3 = S - P; S += P;
    P = lshfl<4>(S, p32, p16); D4 = S - P; S += P;
    P = lshfl<5>(S, p32, p16); D5 = S - P;

    D0 += lshfl<1>(D0, p32, p16); D0 += lshfl<2>(D0, p32, p16);
    D0 += lshfl<3>(D0, p32, p16); D0 += lshfl<4>(D0, p32, p16); D0 += lshfl<5>(D0, p32, p16);
    D1 += lshfl<2>(D1, p32, p16); D1 += lshfl<3>(D1, p32, p16);
    D1 += lshfl<4>(D1, p32, p16); D1 += lshfl<5>(D1, p32, p16);
    D2 += lshfl<3>(D2, p32, p16); D2 += lshfl<4>(D2, p32, p16); D2 += lshfl<5>(D2, p32, p16);
    D3 += lshfl<4>(D3, p32, p16); D3 += lshfl<5>(D3, p32, p16);
    D4 += lshfl<5>(D4, p32, p16);

    if (lane == 0) {
        // qubit i (2..7) = lane bit 7-i -> D_{7-i}
        float4* o = (float4*)(out + b * 8);
        o[0] = make_float4(z0, z1, D5, D4);
        o[1] = make_float4(D3, D2, D1, D0);
    }
}

extern "C" void kernel_launch(void* const* d_in, const int* in_sizes, int n_in,
                              void* d_out, int out_size, void* d_ws, size_t ws_size,
                              hipStream_t stream) {
    const float* x      = (const float*)d_in[0];   // (BATCH, 8)
    const float* params = (const float*)d_in[1];   // (2, 8, 3) = 48
    float* out = (float*)d_out;

    int batch  = in_sizes[0] / 8;
    int blocks = (batch * 64 + 255) / 256;
    qa_sim<<<blocks, 256, 0, stream>>>(x, params, out, batch);
}

// Round 7
// 28.211 us; speedup vs baseline: 1.1635x; 1.1635x over previous
//
#include <hip/hip_runtime.h>

#define DEV __device__ __forceinline__

typedef unsigned u32;
typedef u32 u32x2 __attribute__((ext_vector_type(2)));

// ---------- DPP helpers (ctrl/masks must be ICEs -> template params) ----------

template<int CTRL>
DEV int dpp_full(int src) {
    return __builtin_amdgcn_update_dpp(src, src, CTRL, 0xF, 0xF, false);
}
template<int CTRL, int RM, int BM>
DEV int dpp_masked(int old, int src) {
    return __builtin_amdgcn_update_dpp(old, src, CTRL, RM, BM, false);
}

// ---------- cross-lane xor-shuffle (r4-proven mix) ----------
// xor1/2/8 -> DPP (VALU); xor4/16 -> imm ds_swizzle (DS, overlaps VALU);
// xor32 -> permlane32_swap (VALU) + runtime-probed select.

template<int B>
DEV float lshfl(float x, bool px) {
    int xi = __float_as_int(x);
    if constexpr (B == 0) {
        return __int_as_float(dpp_full<0xB1>(xi));          // quad_perm [1,0,3,2]
    } else if constexpr (B == 1) {
        return __int_as_float(dpp_full<0x4E>(xi));          // quad_perm [2,3,0,1]
    } else if constexpr (B == 2) {
        return __int_as_float(__builtin_amdgcn_ds_swizzle(xi, 0x101F)); // xor4
    } else if constexpr (B == 3) {
        return __int_as_float(dpp_full<0x128>(xi));         // row_ror:8 = xor8
    } else if constexpr (B == 4) {
        return __int_as_float(__builtin_amdgcn_ds_swizzle(xi, 0x401F)); // xor16
    } else {
        u32x2 r = __builtin_amdgcn_permlane32_swap((u32)xi, (u32)xi, false, false);
        return __int_as_float((int)(px ? r.x : r.y));
    }
}

DEV bool probe32(int lane) {
    u32 p = (u32)((lane >> 5) & 1);
    u32x2 r = __builtin_amdgcn_permlane32_swap(p, p, false, false);
    return r.x == (p ^ 1u);
}

// ---------- complex pair primitives (fp32) ----------

DEV void rx_pair(float& r0, float& i0, float& r1, float& i1, float c, float s) {
    float nr0 = fmaf(c, r0,  s * i1);
    float ni0 = fmaf(c, i0, -s * r1);
    float nr1 = fmaf(c, r1,  s * i0);
    float ni1 = fmaf(c, i1, -s * r0);
    r0 = nr0; i0 = ni0; r1 = nr1; i1 = ni1;
}

DEV void ry_pair(float& r0, float& i0, float& r1, float& i1, float c, float s) {
    float nr0 = fmaf(c, r0, -s * r1);
    float ni0 = fmaf(c, i0, -s * i1);
    float nr1 = fmaf(c, r1,  s * r0);
    float ni1 = fmaf(c, i1,  s * i0);
    r0 = nr0; i0 = ni0; r1 = nr1; i1 = ni1;
}

DEV void rz_amp(float& r, float& i, float c, float ss) {
    float nr = fmaf(c, r, -ss * i);
    float ni = fmaf(c, i,  ss * r);
    r = nr; i = ni;
}

// ---------- gates on flat-index bit B (B = 7 - qubit) ----------
// layout: amp idx = k*64 + lane; bits 0..5 = lane bits, 6 = k bit0, 7 = k bit1

template<int B>
DEV void apply_rx(float (&re)[4], float (&im)[4], int lane, bool px, float c, float s) {
    if constexpr (B == 7) {
        rx_pair(re[0], im[0], re[2], im[2], c, s);
        rx_pair(re[1], im[1], re[3], im[3], c, s);
    } else if constexpr (B == 6) {
        rx_pair(re[0], im[0], re[1], im[1], c, s);
        rx_pair(re[2], im[2], re[3], im[3], c, s);
    } else {
#pragma unroll
        for (int k = 0; k < 4; ++k) {
            float pr = lshfl<B>(re[k], px);
            float pi = lshfl<B>(im[k], px);
            re[k] = fmaf(c, re[k],  s * pi);   // RX symmetric: no hi/lo branch
            im[k] = fmaf(c, im[k], -s * pr);
        }
    }
}

template<int B>
DEV void apply_ry(float (&re)[4], float (&im)[4], int lane, bool px, float c, float s) {
    if constexpr (B == 7) {
        ry_pair(re[0], im[0], re[2], im[2], c, s);
        ry_pair(re[1], im[1], re[3], im[3], c, s);
    } else if constexpr (B == 6) {
        ry_pair(re[0], im[0], re[1], im[1], c, s);
        ry_pair(re[2], im[2], re[3], im[3], c, s);
    } else {
        float ssel = ((lane >> B) & 1) ? s : -s;
#pragma unroll
        for (int k = 0; k < 4; ++k) {
            float pr = lshfl<B>(re[k], px);
            float pi = lshfl<B>(im[k], px);
            re[k] = fmaf(c, re[k], ssel * pr);
            im[k] = fmaf(c, im[k], ssel * pi);
        }
    }
}

template<int B>
DEV void apply_rz(float (&re)[4], float (&im)[4], int lane, float c, float s) {
    if constexpr (B == 7) {
        rz_amp(re[0], im[0], c, -s); rz_amp(re[1], im[1], c, -s);
        rz_amp(re[2], im[2], c,  s); rz_amp(re[3], im[3], c,  s);
    } else if constexpr (B == 6) {
        rz_amp(re[0], im[0], c, -s); rz_amp(re[1], im[1], c,  s);
        rz_amp(re[2], im[2], c, -s); rz_amp(re[3], im[3], c,  s);
    } else {
        float ss = ((lane >> B) & 1) ? s : -s;
#pragma unroll
        for (int k = 0; k < 4; ++k) rz_amp(re[k], im[k], c, ss);
    }
}

// CNOT(ctrl=BC, tgt=BT): masked DPP where possible (1 instr per value).
template<int BC, int BT>
DEV void apply_cnot(float (&re)[4], float (&im)[4], int lane, bool px) {
    if constexpr (BC == 7 && BT == 6) {
        float tr = re[2], ti = im[2];
        re[2] = re[3]; im[2] = im[3];
        re[3] = tr;    im[3] = ti;
    } else if constexpr (BC == 6) {
        // ctrl = k bit0 (k=1,3 always on): unconditional xor32 swap
        re[1] = lshfl<5>(re[1], px); im[1] = lshfl<5>(im[1], px);
        re[3] = lshfl<5>(re[3], px); im[3] = lshfl<5>(im[3], px);
    } else if constexpr (BC == 5 && BT == 4) {
        bool ctrl = (lane >> 5) & 1;
#pragma unroll
        for (int k = 0; k < 4; ++k) {
            float pr = lshfl<4>(re[k], px);
            float pi = lshfl<4>(im[k], px);
            re[k] = ctrl ? pr : re[k];
            im[k] = ctrl ? pi : im[k];
        }
    } else if constexpr (BC == 4 && BT == 3) {
        // ctrl = lane bit4 -> rows 1,3 (row_mask 0xA); xor8 = row_ror:8
#pragma unroll
        for (int k = 0; k < 4; ++k) {
            int r = __float_as_int(re[k]), i = __float_as_int(im[k]);
            re[k] = __int_as_float(dpp_masked<0x128, 0xA, 0xF>(r, r));
            im[k] = __int_as_float(dpp_masked<0x128, 0xA, 0xF>(i, i));
        }
    } else if constexpr (BC == 3 && BT == 2) {
        // ctrl = lane bit3 -> banks 2,3 (bank_mask 0xC); xor4 = xor3 then xor7
#pragma unroll
        for (int k = 0; k < 4; ++k) {
            int r = __float_as_int(re[k]), i = __float_as_int(im[k]);
            int tr = dpp_full<0x1B>(r), ti = dpp_full<0x1B>(i);
            re[k] = __int_as_float(dpp_masked<0x141, 0xF, 0xC>(r, tr));
            im[k] = __int_as_float(dpp_masked<0x141, 0xF, 0xC>(i, ti));
        }
    } else if constexpr (BC == 2 && BT == 1) {
        // ctrl = lane bit2 -> banks 1,3 (bank_mask 0xA); xor2 = quad_perm 0x4E
#pragma unroll
        for (int k = 0; k < 4; ++k) {
            int r = __float_as_int(re[k]), i = __float_as_int(im[k]);
            re[k] = __int_as_float(dpp_masked<0x4E, 0xF, 0xA>(r, r));
            im[k] = __int_as_float(dpp_masked<0x4E, 0xF, 0xA>(i, i));
        }
    } else {
        // BC==1, BT==0: quad_perm [0,1,3,2] = 0xB4
#pragma unroll
        for (int k = 0; k < 4; ++k) {
            re[k] = __int_as_float(dpp_full<0xB4>(__float_as_int(re[k])));
            im[k] = __int_as_float(dpp_full<0xB4>(__float_as_int(im[k])));
        }
    }
}

// ---------- prep: cos/sin of 48 shared params into ws ----------

__global__ void qa_prep(const float* __restrict__ params, float* __restrict__ gc, int n) {
    int t = blockIdx.x * blockDim.x + threadIdx.x;
    if (t < n) {
        float th = params[t] * 0.5f;
        gc[2 * t]     = cosf(th);
        gc[2 * t + 1] = sinf(th);
    }
}

// ---------- main: one wave per batch element ----------

__global__ __launch_bounds__(256, 8) void qa_sim(
    const float* __restrict__ x, const float* __restrict__ gc,
    float* __restrict__ out, int batch)
{
    int tid  = blockIdx.x * 256 + threadIdx.x;
    int b    = tid >> 6;
    int lane = threadIdx.x & 63;
    if (b >= batch) return;

    bool px = probe32(lane);

    // ---- bulk-hoist all 96 shared cos/sin values (uniform -> wide s_loads) ----
    float g[96];
#pragma unroll
    for (int i = 0; i < 96; ++i) g[i] = gc[i];

    // ---- direct product-state encoding ----
    // RX(x_i)^{(i)} |0..0>  =>  amp(idx) = (prod mag) * (-i)^popcount(idx),
    // mag factor for qubit i = bit(7-i)(idx) ? sin(x_i/2) : cos(x_i/2).
    const float* xb = x + b * 8;
    float4 xlo = *(const float4*)xb;
    float4 xhi = *(const float4*)(xb + 4);
    float c_[8], s_[8];
    __sincosf(xlo.x * 0.5f, &s_[0], &c_[0]);
    __sincosf(xlo.y * 0.5f, &s_[1], &c_[1]);
    __sincosf(xlo.z * 0.5f, &s_[2], &c_[2]);
    __sincosf(xlo.w * 0.5f, &s_[3], &c_[3]);
    __sincosf(xhi.x * 0.5f, &s_[4], &c_[4]);
    __sincosf(xhi.y * 0.5f, &s_[5], &c_[5]);
    __sincosf(xhi.z * 0.5f, &s_[6], &c_[6]);
    __sincosf(xhi.w * 0.5f, &s_[7], &c_[7]);

    // qubits 2..7 live on lane bits 5..0
    float m6;
    m6  = ((lane >> 5) & 1) ? s_[2] : c_[2];
    m6 *= ((lane >> 4) & 1) ? s_[3] : c_[3];
    m6 *= ((lane >> 3) & 1) ? s_[4] : c_[4];
    m6 *= ((lane >> 2) & 1) ? s_[5] : c_[5];
    m6 *= ((lane >> 1) & 1) ? s_[6] : c_[6];
    m6 *= ( lane       & 1) ? s_[7] : c_[7];
    // k bit0 = flat bit6 = qubit1; k bit1 = flat bit7 = qubit0
    float kf[4] = { c_[0] * c_[1], c_[0] * s_[1], s_[0] * c_[1], s_[0] * s_[1] };
    const int kpc[4] = { 0, 1, 1, 2 };
    int pcl = __popc((u32)lane);

    float re[4], im[4];
#pragma unroll
    for (int k = 0; k < 4; ++k) {
        float mk = m6 * kf[k];
        int p = pcl + kpc[k];
        float sgn = (p & 2) ? -mk : mk;   // (-i)^p real part sign when even
        re[k] = (p & 1) ? 0.f : sgn;
        im[k] = (p & 1) ? -sgn : 0.f;
    }

    // ---- variational layers: g[2*j],g[2*j+1] = cos,sin of params[l][i][{RY,RZ,RX}] ----
#define VQ(l, i) { const int j = (l) * 24 + (i) * 3;                       \
                   apply_ry<7 - (i)>(re, im, lane, px, g[2*j],   g[2*j+1]);   \
                   apply_rz<7 - (i)>(re, im, lane,     g[2*j+2], g[2*j+3]); }
#define CN(i)    apply_cnot<7 - (i), 6 - (i)>(re, im, lane, px);
#define RXQ(l,i) { const int j = (l) * 24 + (i) * 3 + 2;                   \
                   apply_rx<7 - (i)>(re, im, lane, px, g[2*j], g[2*j+1]); }
#define LAYER(l) \
    VQ(l,0) CN(0) VQ(l,1) CN(1) VQ(l,2) CN(2) VQ(l,3) CN(3) \
    VQ(l,4) CN(4) VQ(l,5) CN(5) VQ(l,6) CN(6) VQ(l,7)       \
    RXQ(l,0) RXQ(l,1) RXQ(l,2) RXQ(l,3) RXQ(l,4) RXQ(l,5) RXQ(l,6) RXQ(l,7)

    LAYER(0)
    LAYER(1)
#undef LAYER
#undef RXQ
#undef CN
#undef VQ

    // ---- <Z_i> readout ----
    float p0 = fmaf(re[0], re[0], im[0] * im[0]);
    float p1 = fmaf(re[1], re[1], im[1] * im[1]);
    float p2 = fmaf(re[2], re[2], im[2] * im[2]);
    float p3 = fmaf(re[3], re[3], im[3] * im[3]);

    float z0 = (p0 + p1) - (p2 + p3);   // qubit0 = bit7 = k bit1
    float z1 = (p0 - p1) + (p2 - p3);   // qubit1 = bit6 = k bit0
    float A  = (p0 + p1) + (p2 + p3);   // total prob per lane

    z0 += lshfl<0>(z0, px); z1 += lshfl<0>(z1, px);
    z0 += lshfl<1>(z0, px); z1 += lshfl<1>(z1, px);
    z0 += lshfl<2>(z0, px); z1 += lshfl<2>(z1, px);
    z0 += lshfl<3>(z0, px); z1 += lshfl<3>(z1, px);
    z0 += lshfl<4>(z0, px); z1 += lshfl<4>(z1, px);
    z0 += lshfl<5>(z0, px); z1 += lshfl<5>(z1, px);

    // pruned Walsh-Hadamard on A: D_b = signed sum over lane bit b
    float S = A, P, D0, D1, D2, D3, D4, D5;
    P = lshfl<0>(S, px); D0 = S - P; S += P;
    P = lshfl<1>(S, px); D1 = S - P; S += P;
    P = lshfl<2>(S, px); D2 = S - P; S += P;
    P = lshfl<3>(S, px); D3 = S - P; S += P;
    P = lshfl<4>(S, px); D4 = S - P; S += P;
    P = lshfl<5>(S, px); D5 = S - P;

    D0 += lshfl<1>(D0, px); D0 += lshfl<2>(D0, px);
    D0 += lshfl<3>(D0, px); D0 += lshfl<4>(D0, px); D0 += lshfl<5>(D0, px);
    D1 += lshfl<2>(D1, px); D1 += lshfl<3>(D1, px);
    D1 += lshfl<4>(D1, px); D1 += lshfl<5>(D1, px);
    D2 += lshfl<3>(D2, px); D2 += lshfl<4>(D2, px); D2 += lshfl<5>(D2, px);
    D3 += lshfl<4>(D3, px); D3 += lshfl<5>(D3, px);
    D4 += lshfl<5>(D4, px);

    if (lane == 0) {
        // qubit i (2..7) = lane bit 7-i -> D_{7-i}
        float4* o = (float4*)(out + b * 8);
        o[0] = make_float4(z0, z1, D5, D4);
        o[1] = make_float4(D3, D2, D1, D0);
    }
}

extern "C" void kernel_launch(void* const* d_in, const int* in_sizes, int n_in,
                              void* d_out, int out_size, void* d_ws, size_t ws_size,
                              hipStream_t stream) {
    const float* x      = (const float*)d_in[0];   // (BATCH, 8)
    const float* params = (const float*)d_in[1];   // (2, 8, 3) = 48
    float* out = (float*)d_out;
    float* gc  = (float*)d_ws;                     // 96 floats of (cos,sin)

    int batch   = in_sizes[0] / 8;
    int nparams = in_sizes[1];                     // 48

    qa_prep<<<1, 64, 0, stream>>>(params, gc, nparams);

    int blocks = (batch * 64 + 255) / 256;
    qa_sim<<<blocks, 256, 0, stream>>>(x, gc, out, batch);
}